// Round 6
// baseline (1031.253 us; speedup 1.0000x reference)
//
#include <hip/hip_runtime.h>

// ---------------------------------------------------------------------------
// 2-layer hetero GraphSAGE, bipartite user<->item, H=256.
// Round 8: (a) REVERT round-7's half-column agg split (falsified: FETCH is
// L2-miss traffic; splitting halved effective BW 3.9->2.9 TB/s). (b) Overlap
// the two independent graph chains: each compute-bound GEMM is fused with a
// ready memory-bound agg in ONE dispatch via block-role interleave (every
// S-th block = GEMM, S odd so GEMM blocks spread across XCDs):
//   D1 A_i-agg | D2 gemm_l1_item || A_u-agg | D3 gemm_l1_user || B_u-agg
//   | D4 gemm_l2_user || B_i-agg | D5 gemm_l2_item.
// MFMA waves and gather waves co-schedule on a CU (m114) -> each pair costs
// ~max(gemm, agg) instead of the sum. CSR build + converts from round 7.
// ---------------------------------------------------------------------------

typedef unsigned short u16;
typedef unsigned int u32;
typedef short bf16x8 __attribute__((ext_vector_type(8)));   // 8 bf16 (4 VGPRs)
typedef float f32x4 __attribute__((ext_vector_type(4)));    // MFMA acc

constexpr int HDIM = 256;
constexpr int RB = 128;       // dst rows per bucket (b = dst >> 7)
constexpr int MAXB = 784;     // max buckets: ceil(100000/128) = 782
constexpr int CHUNK = 4096;   // edges per scatter block

// ---------------- bf16 helpers ----------------

__device__ __forceinline__ float lo2f(u32 v) { union { u32 i; float f; } x; x.i = v << 16; return x.f; }
__device__ __forceinline__ float hi2f(u32 v) { union { u32 i; float f; } x; x.i = v & 0xffff0000u; return x.f; }
__device__ __forceinline__ u16 f2bf(float f) {  // RNE
    union { float f; u32 i; } x; x.f = f;
    return (u16)((x.i + 0x7fffu + ((x.i >> 16) & 1u)) >> 16);
}
__device__ __forceinline__ u32 pack2(float a, float b) {
    return (u32)f2bf(a) | ((u32)f2bf(b) << 16);
}

__device__ __forceinline__ void gload16(const void* g, void* l) {
    __builtin_amdgcn_global_load_lds(
        (const __attribute__((address_space(1))) unsigned int*)g,
        (__attribute__((address_space(3))) unsigned int*)l, 16, 0, 0);
}

// ---------------- CSR build (5 launches, unchanged from round 7) ----------------

__global__ __launch_bounds__(256) void bucket_count(const int* __restrict__ dst0, int nb0,
                                                    int* __restrict__ bc0,
                                                    const int* __restrict__ dst1, int nb1,
                                                    int* __restrict__ bc1,
                                                    int E, int sgrid) {
    __shared__ int lcnt[MAXB];
    int b = blockIdx.x;
    const int* dst; int nb; int* bc;
    if (b < sgrid) { dst = dst0; nb = nb0; bc = bc0; }
    else           { b -= sgrid; dst = dst1; nb = nb1; bc = bc1; }
    const int t = threadIdx.x;
    for (int i = t; i < nb; i += 256) lcnt[i] = 0;
    __syncthreads();
    const int base = b * CHUNK;
#pragma unroll
    for (int j = 0; j < CHUNK / 256; j++) {
        int i = base + j * 256 + t;
        if (i < E) atomicAdd(&lcnt[dst[i] >> 7], 1);
    }
    __syncthreads();
    for (int i = t; i < nb; i += 256) {
        int c = lcnt[i];
        if (c) atomicAdd(&bc[i], c);
    }
}

__global__ __launch_bounds__(1024) void bucket_scan(const int* __restrict__ bc0,
                                                    int* __restrict__ base0,
                                                    int* __restrict__ bcur0, int nb0,
                                                    const int* __restrict__ bc1,
                                                    int* __restrict__ base1,
                                                    int* __restrict__ bcur1, int nb1) {
    __shared__ int s[1024];
    const int t = threadIdx.x;
    int own = (t < nb0) ? bc0[t] : 0;
    s[t] = own;
    __syncthreads();
    for (int st = 1; st < 1024; st <<= 1) {
        int v = (t >= st) ? s[t - st] : 0;
        __syncthreads();
        s[t] += v;
        __syncthreads();
    }
    if (t < nb0) { int ex = s[t] - own; base0[t] = ex; bcur0[t] = ex; }
    if (t == 0) base0[nb0] = s[1023];
    __syncthreads();
    own = (t < nb1) ? bc1[t] : 0;
    s[t] = own;
    __syncthreads();
    for (int st = 1; st < 1024; st <<= 1) {
        int v = (t >= st) ? s[t - st] : 0;
        __syncthreads();
        s[t] += v;
        __syncthreads();
    }
    if (t < nb1) { int ex = s[t] - own; base1[t] = ex; bcur1[t] = ex; }
    if (t == 0) base1[nb1] = s[1023];
}

__global__ __launch_bounds__(256) void binned_scatter2(
    const int* __restrict__ src0, const int* __restrict__ dst0, int nb0,
    int* __restrict__ bcur0, u32* __restrict__ pairs0,
    const int* __restrict__ src1, const int* __restrict__ dst1, int nb1,
    int* __restrict__ bcur1, u32* __restrict__ pairs1,
    int E, int sgrid) {
    __shared__ int lcnt[MAXB];
    __shared__ int lbase[MAXB];
    int b = blockIdx.x;
    const int *src, *dst; int nb; int* bcur; u32* pairs;
    if (b < sgrid) { src = src0; dst = dst0; nb = nb0; bcur = bcur0; pairs = pairs0; }
    else           { b -= sgrid; src = src1; dst = dst1; nb = nb1; bcur = bcur1; pairs = pairs1; }
    const int t = threadIdx.x;
    const int chunk = b * CHUNK;

    for (int i = t; i < nb; i += 256) lcnt[i] = 0;
    __syncthreads();

    u32 ss[CHUNK / 256], dd[CHUNK / 256];
#pragma unroll
    for (int j = 0; j < CHUNK / 256; j++) {
        int i = chunk + j * 256 + t;
        if (i < E) {
            ss[j] = (u32)src[i];
            dd[j] = (u32)dst[i];
            atomicAdd(&lcnt[dd[j] >> 7], 1);
        } else {
            ss[j] = 0; dd[j] = 0;
        }
    }
    __syncthreads();

    for (int i = t; i < nb; i += 256) {
        int c = lcnt[i];
        lbase[i] = (c > 0) ? atomicAdd(&bcur[i], c) : 0;
    }
    __syncthreads();
    for (int i = t; i < nb; i += 256) lcnt[i] = 0;  // reuse as rank counters
    __syncthreads();

#pragma unroll
    for (int j = 0; j < CHUNK / 256; j++) {
        int i = chunk + j * 256 + t;
        if (i < E) {
            int bb = (int)(dd[j] >> 7);
            int r = atomicAdd(&lcnt[bb], 1);
            pairs[(size_t)lbase[bb] + r] = (ss[j] << 7) | (dd[j] & 127u);
        }
    }
}

__global__ __launch_bounds__(256) void bucket_fill2(
    const u32* __restrict__ pairs0, const int* __restrict__ base0, int nb0, int n0,
    int* __restrict__ rp0, int* __restrict__ col0,
    const u32* __restrict__ pairs1, const int* __restrict__ base1, int n1,
    int* __restrict__ rp1, int* __restrict__ col1) {
    __shared__ int rcnt[RB];
    __shared__ int excl[RB];
    __shared__ int lcur[RB];
    int b = blockIdx.x;
    const u32* pairs; const int* bb; int n; int* rp; int* col;
    if (b < nb0) { pairs = pairs0; bb = base0; n = n0; rp = rp0; col = col0; }
    else         { b -= nb0; pairs = pairs1; bb = base1; n = n1; rp = rp1; col = col1; }
    const int t = threadIdx.x;
    const int r0 = b * RB;
    const int e0 = bb[b], e1 = bb[b + 1];

    if (t < RB) rcnt[t] = 0;
    __syncthreads();
    for (int j = e0 + t; j < e1; j += 256) atomicAdd(&rcnt[pairs[j] & (RB - 1)], 1);
    __syncthreads();
    int own = (t < RB) ? rcnt[t] : 0;
    if (t < RB) excl[t] = own;
    __syncthreads();
    for (int st = 1; st < RB; st <<= 1) {
        int v = (t < RB && t >= st) ? excl[t - st] : 0;
        __syncthreads();
        if (t < RB) excl[t] += v;
        __syncthreads();
    }
    if (t < RB) {
        int ex = e0 + excl[t] - own;
        int row = r0 + t;
        if (row < n) rp[row] = ex;
        lcur[t] = ex;
    }
    if (t == 0 && r0 + RB >= n) rp[n] = e1;
    __syncthreads();
    for (int j = e0 + t; j < e1; j += 256) {
        u32 e = pairs[j];
        int p = atomicAdd(&lcur[e & (RB - 1)], 1);
        col[p] = (int)(e >> 7);
    }
}

// ---------------- fused fp32 -> bf16 convert ----------------

struct ConvSeg { const float* in; u16* out; u32 n4; u32 pad; };
struct ConvArgs { ConvSeg s[10]; u32 tot; };

__global__ __launch_bounds__(256) void multi_convert(ConvArgs a) {
    for (u32 i = blockIdx.x * 256 + threadIdx.x; i < a.tot; i += gridDim.x * 256) {
        u32 r = i;
        int sg = 0;
        while (r >= a.s[sg].n4) { r -= a.s[sg].n4; sg++; }
        float4 v = ((const float4*)a.s[sg].in)[r];
        ((uint2*)a.s[sg].out)[r] = make_uint2(pack2(v.x, v.y), pack2(v.z, v.w));
    }
}

// ---------------- mean aggregation (device body): subgroup-per-row ----------------

template <int F>
__device__ __forceinline__ void agg_row(const u16* __restrict__ src, const int* __restrict__ rp,
                                        const int* __restrict__ col, u16* __restrict__ out,
                                        int n_dst, int d) {
    constexpr int G = F / 8;     // lanes per row
    constexpr int R = 64 / G;    // rows in flight per issue
    const int lane = threadIdx.x & 63;
    if (d >= n_dst) return;
    const int sub = lane / G;
    const int li = lane & (G - 1);
    const int e0 = rp[d], e1 = rp[d + 1];
    const size_t lo = (size_t)li * 8;

    float a[8] = {0.f, 0.f, 0.f, 0.f, 0.f, 0.f, 0.f, 0.f};
    auto add8 = [&](uint4 v) {
        a[0] += lo2f(v.x); a[1] += hi2f(v.x);
        a[2] += lo2f(v.y); a[3] += hi2f(v.y);
        a[4] += lo2f(v.z); a[5] += hi2f(v.z);
        a[6] += lo2f(v.w); a[7] += hi2f(v.w);
    };

    int ebase = e0;
    for (; ebase + 8 * R <= e1; ebase += 8 * R) {
        int c[8];
#pragma unroll
        for (int k = 0; k < 8; k++) c[k] = col[ebase + sub + k * R];
        uint4 v[8];
#pragma unroll
        for (int k = 0; k < 8; k++) v[k] = *(const uint4*)(src + (size_t)c[k] * F + lo);
#pragma unroll
        for (int k = 0; k < 8; k++) add8(v[k]);
    }
    for (; ebase + 4 * R <= e1; ebase += 4 * R) {
        int c[4];
#pragma unroll
        for (int k = 0; k < 4; k++) c[k] = col[ebase + sub + k * R];
        uint4 v[4];
#pragma unroll
        for (int k = 0; k < 4; k++) v[k] = *(const uint4*)(src + (size_t)c[k] * F + lo);
#pragma unroll
        for (int k = 0; k < 4; k++) add8(v[k]);
    }
    for (int e = ebase + sub; e < e1; e += R) {
        uint4 v = *(const uint4*)(src + (size_t)col[e] * F + lo);
        add8(v);
    }

#pragma unroll
    for (int m = G; m < 64; m <<= 1) {
#pragma unroll
        for (int j = 0; j < 8; j++) a[j] += __shfl_xor(a[j], m, 64);
    }

    const int deg = e1 - e0;
    const float inv = (deg > 0) ? 1.f / (float)deg : 0.f;
    if (lane < G) {
        uint4 w;
        w.x = pack2(a[0] * inv, a[1] * inv);
        w.y = pack2(a[2] * inv, a[3] * inv);
        w.z = pack2(a[4] * inv, a[5] * inv);
        w.w = pack2(a[6] * inv, a[7] * inv);
        *(uint4*)(out + (size_t)d * F + lo) = w;
    }
}

// ---------------- MFMA GEMM body (m97 structure, round-4 proven) ----------------
// out[Mx256] = [A | X] @ [WA | WB]^T + bias   (K = KA + KB, W row-major [256][K*])
// mfma_f32_16x16x32_bf16 layouts (HW-verified):
//   A: lane holds A[m=lane&15][k=ql*8+j]
//   B: lane holds B[k=ql*8+j][n=lane&15] = W[n][k]
//   C/D: col=lane&15, row=ql*4+reg

template <int KA, int KB, bool RELU, bool OUT_BF16>
__device__ __forceinline__ void gemm_body(int vb, u16* Al, u16* Wl,
                                          const u16* __restrict__ A,
                                          const u16* __restrict__ X,
                                          const u16* __restrict__ WA,
                                          const u16* __restrict__ WB,
                                          const float* __restrict__ bias,
                                          float* __restrict__ outF,
                                          u16* __restrict__ outB, int M) {
    constexpr int KT = KA + KB;
    constexpr int NKT = KT / 32;
    const int mb = vb >> 1;
    const int nb = vb & 1;
    const int row0 = mb * 128;
    const int ncol0 = nb * 128;

    const int tid = threadIdx.x;
    const int lane = tid & 63;
    const int wid = tid >> 6;
    const int wr = wid >> 1;
    const int wc = wid & 1;
    const int ml = lane & 15;
    const int ql = lane >> 4;
    const int lrow4 = lane >> 2;
    const int lcol8 = (lane & 3) * 8;

    f32x4 acc[4][4];
#pragma unroll
    for (int m = 0; m < 4; m++)
#pragma unroll
        for (int n = 0; n < 4; n++) acc[m][n] = {0.f, 0.f, 0.f, 0.f};

    const int s0 = wid * 2;

#pragma unroll
    for (int kt = 0; kt < NKT; ++kt) {
        const int kk = kt * 32;
#pragma unroll
        for (int j = 0; j < 2; ++j) {
            const int s = s0 + j;
            int gr = row0 + s * 16 + lrow4;
            gr = (gr < M) ? gr : (M - 1);
            const u16* gp = (kk < KA) ? (A + (size_t)gr * KA + (kk + lcol8))
                                      : (X + (size_t)gr * KB + (kk - KA + lcol8));
            gload16(gp, &Al[s * 512]);
        }
#pragma unroll
        for (int j = 0; j < 2; ++j) {
            const int s = s0 + j;
            const int gn = ncol0 + s * 16 + lrow4;
            const u16* gp = (kk < KA) ? (WA + (size_t)gn * KA + (kk + lcol8))
                                      : (WB + (size_t)gn * KB + (kk - KA + lcol8));
            gload16(gp, &Wl[s * 512]);
        }
        __syncthreads();

        bf16x8 af[4], wf[4];
#pragma unroll
        for (int m = 0; m < 4; m++)
            af[m] = *(const bf16x8*)&Al[(wr * 64 + m * 16 + ml) * 32 + ql * 8];
#pragma unroll
        for (int n = 0; n < 4; n++)
            wf[n] = *(const bf16x8*)&Wl[(wc * 64 + n * 16 + ml) * 32 + ql * 8];
#pragma unroll
        for (int m = 0; m < 4; m++)
#pragma unroll
            for (int n = 0; n < 4; n++)
                acc[m][n] = __builtin_amdgcn_mfma_f32_16x16x32_bf16(af[m], wf[n], acc[m][n], 0, 0, 0);
        __syncthreads();
    }

#pragma unroll
    for (int n = 0; n < 4; n++) {
        const int gcol = ncol0 + wc * 64 + n * 16 + ml;
        const float bv = bias[gcol];
#pragma unroll
        for (int m = 0; m < 4; m++) {
            const int gr0 = row0 + wr * 64 + m * 16 + ql * 4;
#pragma unroll
            for (int rr = 0; rr < 4; rr++) {
                const int grow = gr0 + rr;
                if (grow >= M) continue;
                float v = acc[m][n][rr] + bv;
                if (RELU) v = fmaxf(v, 0.f);
                if (OUT_BF16) outB[(size_t)grow * HDIM + gcol] = f2bf(v);
                else          outF[(size_t)grow * HDIM + gcol] = v;
            }
        }
    }
}

// ---------------- fused dispatch: GEMM blocks interleaved with agg blocks ----
// Every S-th block (S odd -> spreads over XCDs) is a GEMM block; the rest agg.

struct FusedArgs {
    const u16* A; const u16* X; const u16* WA; const u16* WB;
    const float* gbias; float* outF; u16* outB; int M; int n_g;
    const u16* asrc; const int* arp; const int* acol; u16* aout; int a_n; int n_a;
    int S; int pad;
};

template <int KA, int KB, bool RELU, bool OUT_BF16, int F>
__global__ __launch_bounds__(256) void fused_ga(FusedArgs a) {
    __shared__ __align__(16) u16 Al[128 * 32];
    __shared__ __align__(16) u16 Wl[128 * 32];
    const int b = blockIdx.x;
    bool isg; int id;
    if (a.n_a == 0)      { isg = true;  id = b; }
    else if (a.n_g == 0) { isg = false; id = b; }
    else {
        const int qq = b / a.S;
        if (b % a.S == 0 && qq < a.n_g) { isg = true; id = qq; }
        else {
            int before = qq + 1;
            if (before > a.n_g) before = a.n_g;
            isg = false; id = b - before;
        }
    }
    if (isg) {
        gemm_body<KA, KB, RELU, OUT_BF16>(id, Al, Wl, a.A, a.X, a.WA, a.WB,
                                          a.gbias, a.outF, a.outB, a.M);
    } else {
        agg_row<F>(a.asrc, a.arp, a.acol, a.aout, a.a_n,
                   id * 4 + ((int)threadIdx.x >> 6));
    }
}

// ---------------- host ----------------

extern "C" void kernel_launch(void* const* d_in, const int* in_sizes, int n_in,
                              void* d_out, int out_size, void* d_ws, size_t ws_size,
                              hipStream_t stream) {
    const float* x_user = (const float*)d_in[0];
    const float* x_item = (const float*)d_in[1];
    const int* eui_src = (const int*)d_in[2];
    const int* eui_dst = (const int*)d_in[3];
    const int* eiu_src = (const int*)d_in[4];
    const int* eiu_dst = (const int*)d_in[5];
    const float* W1l_ui = (const float*)d_in[6];
    const float* b1_ui  = (const float*)d_in[7];
    const float* W1r_ui = (const float*)d_in[8];
    const float* W1l_iu = (const float*)d_in[9];
    const float* b1_iu  = (const float*)d_in[10];
    const float* W1r_iu = (const float*)d_in[11];
    const float* W2l_ui = (const float*)d_in[12];
    const float* b2_ui  = (const float*)d_in[13];
    const float* W2r_ui = (const float*)d_in[14];
    const float* W2l_iu = (const float*)d_in[15];
    const float* b2_iu  = (const float*)d_in[16];
    const float* W2r_iu = (const float*)d_in[17];

    const int DU = 128, DI = 64;
    const int NU = in_sizes[0] / DU;   // 100000
    const int NI = in_sizes[1] / DI;   // 50000
    const int E  = in_sizes[2];        // 1600000

    // ---- carve workspace (256B aligned); ~205 MB total ----
    char* base = (char*)d_ws;
    size_t off = 0;
    auto carve = [&](size_t bytes) -> char* {
        char* p = base + off;
        off += (bytes + 255) & ~(size_t)255;
        return p;
    };
    int* rp_i   = (int*)carve((size_t)(NI + 1) * 4);
    int* rp_u   = (int*)carve((size_t)(NU + 1) * 4);
    int* col_ui = (int*)carve((size_t)E * 4);
    int* col_iu = (int*)carve((size_t)E * 4);
    int* bc     = (int*)carve((size_t)2 * MAXB * 4);
    int* bc_i   = bc;
    int* bc_u   = bc + MAXB;
    int* base_i = (int*)carve((size_t)(MAXB + 1) * 4);
    int* base_u = (int*)carve((size_t)(MAXB + 1) * 4);
    int* bcur_i = (int*)carve(MAXB * 4);
    int* bcur_u = (int*)carve(MAXB * 4);
    // bf16 weights
    u16* W1l_ui_b = (u16*)carve((size_t)HDIM * DU * 2);
    u16* W1r_ui_b = (u16*)carve((size_t)HDIM * DI * 2);
    u16* W1l_iu_b = (u16*)carve((size_t)HDIM * DI * 2);
    u16* W1r_iu_b = (u16*)carve((size_t)HDIM * DU * 2);
    u16* W2l_ui_b = (u16*)carve((size_t)HDIM * HDIM * 2);
    u16* W2r_ui_b = (u16*)carve((size_t)HDIM * HDIM * 2);
    u16* W2l_iu_b = (u16*)carve((size_t)HDIM * HDIM * 2);
    u16* W2r_iu_b = (u16*)carve((size_t)HDIM * HDIM * 2);
    // region1 (25.6 MB): x_user_b [NUx128] (dead after D3) / B_i [NIx256] (D4+)
    char* reg1 = carve((size_t)NU * DU * 2);
    u16* x_user_b = (u16*)reg1;
    u16* B_i      = (u16*)reg1;
    // region2 (32 MB): x_item_b + A_i + A_u (all dead after D3)
    char* reg2 = carve((size_t)NI * DI * 2 + (size_t)NI * DU * 2 + (size_t)NU * DI * 2);
    u16* x_item_b = (u16*)reg2;                                // NI*64*2  = 6.4 MB
    u16* A_i      = (u16*)(reg2 + (size_t)NI * DI * 2);        // NI*128*2 = 12.8 MB
    u16* A_u      = (u16*)(reg2 + (size_t)NI * DI * 2 + (size_t)NI * DU * 2);  // NU*64*2
    // dedicated buffers
    u16* B_u    = (u16*)carve((size_t)NU * HDIM * 2);  // 51.2 MB (written D3)
    u16* h_item = (u16*)carve((size_t)NI * HDIM * 2);  // 25.6 MB (written D2)
    u16* h_user = (u16*)carve((size_t)NU * HDIM * 2);  // 51.2 MB (written D3)

    // packed pairs scratch (2 x 6.4 MB) aliases h_user: dead before D3
    u32* pairs_i = (u32*)h_user;
    u32* pairs_u = pairs_i + E;

    float* out_user = (float*)d_out;
    float* out_item = (float*)d_out + (size_t)NU * HDIM;

    const int nb_i = (NI + RB - 1) / RB;   // 391
    const int nb_u = (NU + RB - 1) / RB;   // 782
    const int sgrid = (E + CHUNK - 1) / CHUNK;

    // ---- CSR build ----
    hipMemsetAsync(bc, 0, (size_t)2 * MAXB * 4, stream);
    bucket_count<<<2 * sgrid, 256, 0, stream>>>(eui_dst, nb_i, bc_i, eiu_dst, nb_u, bc_u, E, sgrid);
    bucket_scan<<<1, 1024, 0, stream>>>(bc_i, base_i, bcur_i, nb_i, bc_u, base_u, bcur_u, nb_u);
    binned_scatter2<<<2 * sgrid, 256, 0, stream>>>(
        eui_src, eui_dst, nb_i, bcur_i, pairs_i,
        eiu_src, eiu_dst, nb_u, bcur_u, pairs_u, E, sgrid);
    bucket_fill2<<<nb_i + nb_u, 256, 0, stream>>>(
        pairs_i, base_i, nb_i, NI, rp_i, col_ui,
        pairs_u, base_u, NU, rp_u, col_iu);

    // ---- converts (1 launch) ----
    {
        ConvArgs ca;
        auto seg = [&](int i, const float* in, u16* outp, size_t n) {
            ca.s[i].in = in; ca.s[i].out = outp; ca.s[i].n4 = (u32)(n / 4); ca.s[i].pad = 0;
        };
        seg(0, x_user, x_user_b, (size_t)NU * DU);
        seg(1, x_item, x_item_b, (size_t)NI * DI);
        seg(2, W2l_ui, W2l_ui_b, (size_t)HDIM * HDIM);
        seg(3, W2r_ui, W2r_ui_b, (size_t)HDIM * HDIM);
        seg(4, W2l_iu, W2l_iu_b, (size_t)HDIM * HDIM);
        seg(5, W2r_iu, W2r_iu_b, (size_t)HDIM * HDIM);
        seg(6, W1l_ui, W1l_ui_b, (size_t)HDIM * DU);
        seg(7, W1r_ui, W1r_ui_b, (size_t)HDIM * DI);
        seg(8, W1l_iu, W1l_iu_b, (size_t)HDIM * DI);
        seg(9, W1r_iu, W1r_iu_b, (size_t)HDIM * DU);
        u32 tot = 0;
        for (int i = 0; i < 10; i++) tot += ca.s[i].n4;
        ca.tot = tot;
        multi_convert<<<2048, 256, 0, stream>>>(ca);
    }

    const int gi = (NI + 3) / 4;            // 12500 agg blocks (item dst)
    const int gu = (NU + 3) / 4;            // 25000 agg blocks (user dst)
    const int ng_i = ((NI + 127) / 128) * 2;  // 782 gemm blocks (M=NI)
    const int ng_u = ((NU + 127) / 128) * 2;  // 1564 gemm blocks (M=NU)

    auto mkS = [](int n_g, int n_a) -> int {
        if (n_g == 0 || n_a == 0) return 1;
        int S = (n_g + n_a) / n_g;
        if (S < 1) S = 1;
        if (S > 1 && (S & 1) == 0) S -= 1;   // odd: spread gemm blocks over XCDs
        return S;
    };
    FusedArgs fa;

    // ---- D1: A_i = mean_ui(x_user)  [agg only, F=128] ----
    fa = {};
    fa.n_g = 0;
    fa.asrc = x_user_b; fa.arp = rp_i; fa.acol = col_ui; fa.aout = A_i; fa.a_n = NI; fa.n_a = gi;
    fa.S = 1;
    fused_ga<128, 64, true, true, 128><<<gi, 256, 0, stream>>>(fa);

    // ---- D2: gemm_l1_item || A_u = mean_iu(x_item)  [F=64] ----
    fa = {};
    fa.A = A_i; fa.X = x_item_b; fa.WA = W1l_ui_b; fa.WB = W1r_ui_b; fa.gbias = b1_ui;
    fa.outF = nullptr; fa.outB = h_item; fa.M = NI; fa.n_g = ng_i;
    fa.asrc = x_item_b; fa.arp = rp_u; fa.acol = col_iu; fa.aout = A_u; fa.a_n = NU; fa.n_a = gu;
    fa.S = mkS(ng_i, gu);
    fused_ga<128, 64, true, true, 64><<<ng_i + gu, 256, 0, stream>>>(fa);

    // ---- D3: gemm_l1_user || B_u = mean_iu(h_item)  [F=256] ----
    fa = {};
    fa.A = A_u; fa.X = x_user_b; fa.WA = W1l_iu_b; fa.WB = W1r_iu_b; fa.gbias = b1_iu;
    fa.outF = nullptr; fa.outB = h_user; fa.M = NU; fa.n_g = ng_u;
    fa.asrc = h_item; fa.arp = rp_u; fa.acol = col_iu; fa.aout = B_u; fa.a_n = NU; fa.n_a = gu;
    fa.S = mkS(ng_u, gu);
    fused_ga<64, 128, true, true, 256><<<ng_u + gu, 256, 0, stream>>>(fa);

    // ---- D4: gemm_l2_user || B_i = mean_ui(h_user)  [F=256] ----
    // (B_i overwrites x_user_b: dead after D3)
    fa = {};
    fa.A = B_u; fa.X = h_user; fa.WA = W2l_iu_b; fa.WB = W2r_iu_b; fa.gbias = b2_iu;
    fa.outF = out_user; fa.outB = nullptr; fa.M = NU; fa.n_g = ng_u;
    fa.asrc = h_user; fa.arp = rp_i; fa.acol = col_ui; fa.aout = B_i; fa.a_n = NI; fa.n_a = gi;
    fa.S = mkS(ng_u, gi);
    fused_ga<256, 256, false, false, 256><<<ng_u + gi, 256, 0, stream>>>(fa);

    // ---- D5: gemm_l2_item  [gemm only] ----
    fa = {};
    fa.A = B_i; fa.X = h_item; fa.WA = W2l_ui_b; fa.WB = W2r_ui_b; fa.gbias = b2_ui;
    fa.outF = out_item; fa.outB = nullptr; fa.M = NI; fa.n_g = ng_i;
    fa.n_a = 0; fa.S = 1;
    fused_ga<256, 256, false, false, 256><<<ng_i, 256, 0, stream>>>(fa);
}